// Round 7
// baseline (576.488 us; speedup 1.0000x reference)
//
#include <hip/hip_runtime.h>
#include <stdint.h>

#define B_   64
#define S_   197
#define D_   768
#define H_   12
#define F_   3072
#define BS_  (B_ * S_)   // 12608

typedef __attribute__((ext_vector_type(8))) short short8;
typedef __attribute__((ext_vector_type(4))) float f32x4;

__device__ __forceinline__ float bf2f(unsigned short h) {
    union { unsigned int u; float f; } v; v.u = ((unsigned int)h) << 16; return v.f;
}
__device__ __forceinline__ unsigned short f2bf(float f) {
    union { float f; unsigned int u; } v; v.f = f;
    unsigned int r = v.u + 0x7FFFu + ((v.u >> 16) & 1u);
    return (unsigned short)(r >> 16);
}

__device__ __forceinline__ void g2l16(const void* g, void* l) {
    __builtin_amdgcn_global_load_lds(
        (const __attribute__((address_space(1))) unsigned int*)g,
        (__attribute__((address_space(3))) unsigned int*)l, 16, 0, 0);
}

// exact-enough GELU: A&S 7.1.26 erf (max abs err 1.5e-7)
__device__ __forceinline__ float gelu_f(float c) {
    float z = fabsf(c) * 0.70710678118f;
    float t = __builtin_amdgcn_rcpf(1.f + 0.3275911f * z);
    float p = ((((1.061405429f * t - 1.453152027f) * t + 1.421413741f) * t
               - 0.284496736f) * t + 0.254829592f) * t;
    float erfv = 1.f - p * __expf(-z * z);
    erfv = c < 0.f ? -erfv : erfv;
    return 0.5f * c * (1.f + erfv);
}

// ---------------- fused weight transpose + bf16 cast + bias concat ----------------
__global__ __launch_bounds__(256)
void transpose_all(const float* __restrict__ Wq, const float* __restrict__ Wk,
                   const float* __restrict__ Wv, const float* __restrict__ Wo,
                   const float* __restrict__ W1, const float* __restrict__ W2,
                   const float* __restrict__ bq, const float* __restrict__ bk,
                   const float* __restrict__ bv,
                   unsigned short* __restrict__ wqkvT, unsigned short* __restrict__ woT,
                   unsigned short* __restrict__ w1T, unsigned short* __restrict__ w2T,
                   float* __restrict__ bcat) {
    int blk = blockIdx.x;
    int tx = threadIdx.x, ty = threadIdx.y;
    if (blk == 6912) {
        for (int i = ty * 32 + tx; i < 2304; i += 256)
            bcat[i] = i < 768 ? bq[i] : (i < 1536 ? bk[i - 768] : bv[i - 1536]);
        return;
    }
    const float* W; unsigned short* Wt; int K, N, rel, nx;
    if (blk < 2304) {
        int m = blk / 576; rel = blk - m * 576; K = 768; N = 768; nx = 24;
        W  = m == 0 ? Wq : m == 1 ? Wk : m == 2 ? Wv : Wo;
        Wt = m < 3 ? wqkvT + (size_t)m * 768 * 768 : woT;
    } else if (blk < 4608) {
        rel = blk - 2304; K = 768; N = 3072; nx = 96; W = W1; Wt = w1T;
    } else {
        rel = blk - 4608; K = 3072; N = 768; nx = 24; W = W2; Wt = w2T;
    }
    int n0 = (rel % nx) * 32, k0 = (rel / nx) * 32;
    __shared__ float t[32][33];
#pragma unroll
    for (int i = ty; i < 32; i += 8) t[i][tx] = W[(size_t)(k0 + i) * N + n0 + tx];
    __syncthreads();
#pragma unroll
    for (int i = ty; i < 32; i += 8) Wt[(size_t)(n0 + i) * K + k0 + tx] = f2bf(t[tx][i]);
}

// ---------------- LayerNorm: f32 in -> bf16 out ----------------
__global__ __launch_bounds__(256)
void ln_kernel(const float* __restrict__ x, const float* __restrict__ w,
               const float* __restrict__ b, unsigned short* __restrict__ out) {
    int row = blockIdx.x; size_t base = (size_t)row * 768;
    int tid = threadIdx.x;
    float v0 = x[base + tid], v1 = x[base + tid + 256], v2 = x[base + tid + 512];
    float s1 = v0 + v1 + v2;
    float s2 = v0 * v0 + v1 * v1 + v2 * v2;
#pragma unroll
    for (int off = 32; off > 0; off >>= 1) { s1 += __shfl_xor(s1, off); s2 += __shfl_xor(s2, off); }
    __shared__ float sa[4], sb[4];
    int w4 = tid >> 6;
    if ((tid & 63) == 0) { sa[w4] = s1; sb[w4] = s2; }
    __syncthreads();
    s1 = sa[0] + sa[1] + sa[2] + sa[3];
    s2 = sb[0] + sb[1] + sb[2] + sb[3];
    float mean = s1 * (1.f / 768.f);
    float var  = s2 * (1.f / 768.f) - mean * mean;
    float rstd = rsqrtf(var + 1e-6f);
    out[base + tid]       = f2bf((v0 - mean) * rstd * w[tid]       + b[tid]);
    out[base + tid + 256] = f2bf((v1 - mean) * rstd * w[tid + 256] + b[tid + 256]);
    out[base + tid + 512] = f2bf((v2 - mean) * rstd * w[tid + 512] + b[tid + 512]);
}

// ---------------- GEMM v4: 256x128 / BK=64, 8 waves, m201-style 4-phase interleave ------
// C[M][N] = A[M][K](bf16) * Bt[N][K](bf16)^T + epilogue.
// LDS: As[2][256][64] (64KB) + Bs[2][128][64] (32KB). Rows are 128B (exact 32-bank wrap);
// 16B-block swizzle phys = log ^ (row&7), write-side via pre-swizzled global source
// (linear LDS dest, rule 21), read-side same XOR. Wave grid 2(M)x4(N): wave tile 128x32.
// Per K-tile: 4 phases (C-quadrants). Phase = {ds_read quadrant A-frags (+B at q0)
//   -> [q0: issue ALL 6 global_load_lds for tile t+1 into buf^1, lag=4 phases]
//   -> s_barrier -> setprio(1) -> 8 MFMA -> setprio(0) -> s_barrier}.
// Tile boundary: vmcnt(0) (stages landed long ago) + barrier + sched_barrier(0).
// MODE 0: bf16 = acc+bias (cols<768 pre-scaled 0.125); MODE 1: f32 = acc+bias+resid;
// MODE 2: bf16 = gelu(acc+bias).
template<int MODE>
__global__ __launch_bounds__(512, 2)
void gemm8p(const unsigned short* __restrict__ A, const unsigned short* __restrict__ Bt,
            const float* __restrict__ bias, const float* __restrict__ resid,
            void* __restrict__ out, int M, int N, int K) {
    __shared__ unsigned short As[2][256 * 64];
    __shared__ unsigned short Bs[2][128 * 64];
    const int tid = threadIdx.x;
    const int l = tid & 63, wid = tid >> 6;
    const int lr = l & 15, lg = l >> 4;
    const int wr = wid >> 2, wc = wid & 3;
    const int bn0 = blockIdx.x * 128, bm0 = blockIdx.y * 256;

    const int srow8 = l >> 3;               // lane's row within its 8-row slab
    const int slb = (l & 7) ^ srow8;        // pre-swizzled logical 16B block for the source

    auto stageA = [&](int buf, int kt, int a) {        // a in 0..3: rows a*64..a*64+63
        int row = a * 64 + wid * 8 + srow8;
        int gr = bm0 + row; gr = gr < M ? gr : M - 1;
        g2l16(A + (size_t)gr * K + kt * 64 + slb * 8, &As[buf][(a * 64 + wid * 8) * 64]);
    };
    auto stageB = [&](int buf, int kt, int b) {        // b in 0..1: rows b*64..b*64+63
        int row = b * 64 + wid * 8 + srow8;
        g2l16(Bt + (size_t)(bn0 + row) * K + kt * 64 + slb * 8, &Bs[buf][(b * 64 + wid * 8) * 64]);
    };

    f32x4 acc[8][2];
#pragma unroll
    for (int i = 0; i < 8; ++i)
#pragma unroll
        for (int j = 0; j < 2; ++j) acc[i][j] = (f32x4){0.f, 0.f, 0.f, 0.f};

    const int NK = K >> 6;                   // 12 or 48
    // prologue: stage tile 0
    stageA(0, 0, 0); stageA(0, 0, 1); stageA(0, 0, 2); stageA(0, 0, 3);
    stageB(0, 0, 0); stageB(0, 0, 1);

    const int rs = lr & 7;                   // read-side row XOR
    for (int t = 0; t < NK; ++t) {
        const int buf = t & 1;
        // ---- tile boundary: all of tile t's stages (issued >=4 phases ago) landed ----
        asm volatile("s_waitcnt vmcnt(0)" ::: "memory");
        __builtin_amdgcn_s_barrier();
        __builtin_amdgcn_sched_barrier(0);   // no reads hoist above the boundary
        short8 bf[2][2];
#pragma unroll
        for (int q = 0; q < 4; ++q) {
            short8 af[2][2];
#pragma unroll
            for (int mt = 0; mt < 2; ++mt)
#pragma unroll
                for (int kk = 0; kk < 2; ++kk)
                    af[mt][kk] = *(const short8*)&As[buf][(wr * 128 + (q * 2 + mt) * 16 + lr) * 64 +
                                                         (((kk * 4 + lg) ^ rs) * 8)];
            if (q == 0) {
#pragma unroll
                for (int nt = 0; nt < 2; ++nt)
#pragma unroll
                    for (int kk = 0; kk < 2; ++kk)
                        bf[nt][kk] = *(const short8*)&Bs[buf][(wc * 32 + nt * 16 + lr) * 64 +
                                                             (((kk * 4 + lg) ^ rs) * 8)];
                if (t + 1 < NK) {            // all next-tile stages here: 4-phase lag
                    stageA(buf ^ 1, t + 1, 0); stageA(buf ^ 1, t + 1, 1);
                    stageA(buf ^ 1, t + 1, 2); stageA(buf ^ 1, t + 1, 3);
                    stageB(buf ^ 1, t + 1, 0); stageB(buf ^ 1, t + 1, 1);
                }
            }
            __builtin_amdgcn_s_barrier();
            __builtin_amdgcn_s_setprio(1);
#pragma unroll
            for (int mt = 0; mt < 2; ++mt)
#pragma unroll
                for (int nt = 0; nt < 2; ++nt)
#pragma unroll
                    for (int kk = 0; kk < 2; ++kk)
                        acc[q * 2 + mt][nt] = __builtin_amdgcn_mfma_f32_16x16x32_bf16(
                            af[mt][kk], bf[nt][kk], acc[q * 2 + mt][nt], 0, 0, 0);
            __builtin_amdgcn_s_setprio(0);
            __builtin_amdgcn_s_barrier();
        }
    }

#pragma unroll
    for (int mt = 0; mt < 8; ++mt)
#pragma unroll
        for (int nt = 0; nt < 2; ++nt)
#pragma unroll
            for (int r = 0; r < 4; ++r) {
                int gm = bm0 + wr * 128 + mt * 16 + lg * 4 + r;
                int gn = bn0 + wc * 32 + nt * 16 + lr;
                if (gm < M) {
                    float c = acc[mt][nt][r] + bias[gn];
                    if (MODE == 0) {
                        if (gn < 768) c *= 0.125f;   // fold 1/sqrt(Dh) into Q
                        ((unsigned short*)out)[(size_t)gm * N + gn] = f2bf(c);
                    } else if (MODE == 1) {
                        ((float*)out)[(size_t)gm * N + gn] = c + resid[(size_t)gm * N + gn];
                    } else {
                        ((unsigned short*)out)[(size_t)gm * N + gn] = f2bf(gelu_f(c));
                    }
                }
            }
}

// ---------------- MFMA attention: one block per (b,h), 4 waves ----------------
__global__ __launch_bounds__(256)
void attn_mfma(const unsigned short* __restrict__ qkv, const int* __restrict__ mask,
               unsigned short* __restrict__ ctx) {
    __shared__ unsigned short Ks[208 * 64];
    __shared__ unsigned short Vt[64 * 256];
    __shared__ unsigned short Psl[4][16 * 40];
    __shared__ float maskadj[224];
    const int bh = blockIdx.x, b = bh / 12, h = bh - b * 12;
    const int tid = threadIdx.x, l = tid & 63, w = tid >> 6;
    const int lr = l & 15, lg = l >> 4;
    const unsigned short* Qg = qkv + (size_t)b * 197 * 2304 + h * 64;
    const unsigned short* Kg = Qg + 768;
    const unsigned short* Vg = Qg + 1536;

    if (tid < 224)
        maskadj[tid] = tid < 197 ? -10000.f * (1.f - (float)mask[b * 197 + tid]) : -1e30f;

    for (int c = w; c < 26; c += 4) {
        int row = c * 8 + (l >> 3);
        int rc = row < 197 ? row : 196;
        int blk = (l & 7) ^ (row & 7);
        g2l16(Kg + (size_t)rc * 2304 + blk * 8, &Ks[c * 8 * 64]);
    }
    {
        int jj = tid >> 3, db = tid & 7;
#pragma unroll
        for (int it = 0; it < 7; ++it) {
            int j = it * 32 + jj;
            short8 v = (short8){0, 0, 0, 0, 0, 0, 0, 0};
            if (j < 197) v = *(const short8*)(Vg + (size_t)j * 2304 + db * 8);
#pragma unroll
            for (int e = 0; e < 8; ++e) {
                int d = db * 8 + e;
                Vt[d * 256 + (((j >> 3) ^ (d & 7)) * 8) + (j & 7)] = (unsigned short)v[e];
            }
        }
    }
    __syncthreads();

    for (int t = w; t < 13; t += 4) {
        const int q0 = t * 16;
        int qr = q0 + lr; qr = qr < 197 ? qr : 196;
        const short8 qf0 = *(const short8*)(Qg + (size_t)qr * 2304 + lg * 8);
        const short8 qf1 = *(const short8*)(Qg + (size_t)qr * 2304 + 32 + lg * 8);

        f32x4 sc[13];
#pragma unroll
        for (int kt = 0; kt < 13; ++kt) {
            const int krow = kt * 16 + lr;
            const short8 kf0 = *(const short8*)&Ks[krow * 64 + ((lg ^ (lr & 7)) * 8)];
            const short8 kf1 = *(const short8*)&Ks[krow * 64 + (((4 + lg) ^ (lr & 7)) * 8)];
            f32x4 a = (f32x4){0.f, 0.f, 0.f, 0.f};
            a = __builtin_amdgcn_mfma_f32_16x16x32_bf16(qf0, kf0, a, 0, 0, 0);
            a = __builtin_amdgcn_mfma_f32_16x16x32_bf16(qf1, kf1, a, 0, 0, 0);
            sc[kt] = a;
        }
        float mx[4] = {-1e30f, -1e30f, -1e30f, -1e30f};
#pragma unroll
        for (int kt = 0; kt < 13; ++kt) {
            float ma = maskadj[kt * 16 + lr];
#pragma unroll
            for (int r = 0; r < 4; ++r) {
                sc[kt][r] += ma;
                mx[r] = fmaxf(mx[r], sc[kt][r]);
            }
        }
#pragma unroll
        for (int r = 0; r < 4; ++r) {
            mx[r] = fmaxf(mx[r], __shfl_xor(mx[r], 1));
            mx[r] = fmaxf(mx[r], __shfl_xor(mx[r], 2));
            mx[r] = fmaxf(mx[r], __shfl_xor(mx[r], 4));
            mx[r] = fmaxf(mx[r], __shfl_xor(mx[r], 8));
        }
        float sm[4] = {0.f, 0.f, 0.f, 0.f};
#pragma unroll
        for (int kt = 0; kt < 13; ++kt)
#pragma unroll
            for (int r = 0; r < 4; ++r) {
                float p = __expf(sc[kt][r] - mx[r]);
                sc[kt][r] = p;
                sm[r] += p;
            }
#pragma unroll
        for (int r = 0; r < 4; ++r) {
            sm[r] += __shfl_xor(sm[r], 1);
            sm[r] += __shfl_xor(sm[r], 2);
            sm[r] += __shfl_xor(sm[r], 4);
            sm[r] += __shfl_xor(sm[r], 8);
            sm[r] = 1.f / sm[r];
        }
        f32x4 ao[4];
#pragma unroll
        for (int dt = 0; dt < 4; ++dt) ao[dt] = (f32x4){0.f, 0.f, 0.f, 0.f};
        unsigned short* Pw = &Psl[w][0];
#pragma unroll
        for (int ks = 0; ks < 7; ++ks) {
#pragma unroll
            for (int tl = 0; tl < 2; ++tl) {
                const int kt = ks * 2 + tl;
#pragma unroll
                for (int r = 0; r < 4; ++r) {
                    unsigned short pv = 0;
                    if (kt < 13) pv = f2bf(sc[kt][r] * sm[r]);
                    Pw[(lg * 4 + r) * 40 + tl * 16 + lr] = pv;
                }
            }
            const short8 pf = *(const short8*)&Pw[lr * 40 + lg * 8];
#pragma unroll
            for (int dt = 0; dt < 4; ++dt) {
                const int drow = dt * 16 + lr;
                const short8 vf = *(const short8*)&Vt[drow * 256 + (((4 * ks + lg) ^ (lr & 7)) * 8)];
                ao[dt] = __builtin_amdgcn_mfma_f32_16x16x32_bf16(vf, pf, ao[dt], 0, 0, 0);
            }
        }
        const int q = q0 + lr;
        if (q < 197) {
            unsigned short* crow = ctx + ((size_t)b * 197 + q) * 768 + h * 64;
#pragma unroll
            for (int dt = 0; dt < 4; ++dt) {
                union { unsigned short u[4]; uint2 v; } pk;
#pragma unroll
                for (int r = 0; r < 4; ++r) pk.u[r] = f2bf(ao[dt][r]);
                *(uint2*)(crow + dt * 16 + lg * 4) = pk.v;
            }
        }
    }
}

extern "C" void kernel_launch(void* const* d_in, const int* in_sizes, int n_in,
                              void* d_out, int out_size, void* d_ws, size_t ws_size,
                              hipStream_t stream) {
    const float* x    = (const float*)d_in[0];
    const float* Wq   = (const float*)d_in[1];
    const float* bq   = (const float*)d_in[2];
    const float* Wk   = (const float*)d_in[3];
    const float* bk   = (const float*)d_in[4];
    const float* Wv   = (const float*)d_in[5];
    const float* bv   = (const float*)d_in[6];
    const float* Wo   = (const float*)d_in[7];
    const float* bo   = (const float*)d_in[8];
    const float* ln1w = (const float*)d_in[9];
    const float* ln1b = (const float*)d_in[10];
    const float* W1   = (const float*)d_in[11];
    const float* b1   = (const float*)d_in[12];
    const float* W2   = (const float*)d_in[13];
    const float* b2   = (const float*)d_in[14];
    const float* ln2w = (const float*)d_in[15];
    const float* ln2b = (const float*)d_in[16];
    const int*   mask = (const int*)d_in[17];

    size_t off = 0;
    auto nxt = [&](size_t bytes) -> void* {
        void* r = (char*)d_ws + off; off += (bytes + 255) & ~(size_t)255; return r;
    };
    unsigned short* hbuf  = (unsigned short*)nxt((size_t)BS_ * 768 * 2);
    unsigned short* qkvg  = (unsigned short*)nxt((size_t)BS_ * 3072 * 2);  // QKV (2304), reused for FFN1 out (3072)
    unsigned short* wqkvT = (unsigned short*)nxt((size_t)2304 * 768 * 2);
    unsigned short* woT   = (unsigned short*)nxt((size_t)768 * 768 * 2);
    unsigned short* w1T   = (unsigned short*)nxt((size_t)3072 * 768 * 2);
    unsigned short* w2T   = (unsigned short*)nxt((size_t)768 * 3072 * 2);
    float*          bcat  = (float*)nxt(2304 * 4);
    unsigned short* ctx   = (unsigned short*)nxt((size_t)BS_ * 768 * 2);
    (void)ws_size; (void)in_sizes; (void)n_in; (void)out_size;

    transpose_all<<<6913, dim3(32, 8), 0, stream>>>(Wq, Wk, Wv, Wo, W1, W2, bq, bk, bv,
                                                    wqkvT, woT, w1T, w2T, bcat);
    ln_kernel<<<BS_, 256, 0, stream>>>(x, ln1w, ln1b, hbuf);
    gemm8p<0><<<dim3(18, 50), 512, 0, stream>>>(hbuf, wqkvT, bcat, nullptr, qkvg, BS_, 2304, 768);
    attn_mfma<<<768, 256, 0, stream>>>(qkvg, mask, ctx);
    gemm8p<1><<<dim3(6, 50), 512, 0, stream>>>(ctx, woT, bo, x, d_out, BS_, 768, 768);
    ln_kernel<<<BS_, 256, 0, stream>>>((const float*)d_out, ln2w, ln2b, hbuf);
    gemm8p<2><<<dim3(24, 50), 512, 0, stream>>>(hbuf, w1T, b1, nullptr, qkvg, BS_, 3072, 768);
    gemm8p<1><<<dim3(6, 50), 512, 0, stream>>>(qkvg, w2T, b2, (const float*)d_out, d_out, BS_, 768, 3072);
}

// Round 8
// 527.184 us; speedup vs baseline: 1.0935x; 1.0935x over previous
//
#include <hip/hip_runtime.h>
#include <stdint.h>

#define B_   64
#define S_   197
#define D_   768
#define H_   12
#define F_   3072
#define BS_  (B_ * S_)   // 12608

typedef __attribute__((ext_vector_type(8))) short short8;
typedef __attribute__((ext_vector_type(4))) float f32x4;

__device__ __forceinline__ float bf2f(unsigned short h) {
    union { unsigned int u; float f; } v; v.u = ((unsigned int)h) << 16; return v.f;
}
__device__ __forceinline__ unsigned short f2bf(float f) {
    union { float f; unsigned int u; } v; v.f = f;
    unsigned int r = v.u + 0x7FFFu + ((v.u >> 16) & 1u);
    return (unsigned short)(r >> 16);
}

__device__ __forceinline__ void g2l16(const void* g, void* l) {
    __builtin_amdgcn_global_load_lds(
        (const __attribute__((address_space(1))) unsigned int*)g,
        (__attribute__((address_space(3))) unsigned int*)l, 16, 0, 0);
}

// exact-enough GELU: A&S 7.1.26 erf (max abs err 1.5e-7)
__device__ __forceinline__ float gelu_f(float c) {
    float z = fabsf(c) * 0.70710678118f;
    float t = __builtin_amdgcn_rcpf(1.f + 0.3275911f * z);
    float p = ((((1.061405429f * t - 1.453152027f) * t + 1.421413741f) * t
               - 0.284496736f) * t + 0.254829592f) * t;
    float erfv = 1.f - p * __expf(-z * z);
    erfv = c < 0.f ? -erfv : erfv;
    return 0.5f * c * (1.f + erfv);
}

// ---------------- fused weight transpose + bf16 cast + bias concat ----------------
__global__ __launch_bounds__(256)
void transpose_all(const float* __restrict__ Wq, const float* __restrict__ Wk,
                   const float* __restrict__ Wv, const float* __restrict__ Wo,
                   const float* __restrict__ W1, const float* __restrict__ W2,
                   const float* __restrict__ bq, const float* __restrict__ bk,
                   const float* __restrict__ bv,
                   unsigned short* __restrict__ wqkvT, unsigned short* __restrict__ woT,
                   unsigned short* __restrict__ w1T, unsigned short* __restrict__ w2T,
                   float* __restrict__ bcat) {
    int blk = blockIdx.x;
    int tx = threadIdx.x, ty = threadIdx.y;
    if (blk == 6912) {
        for (int i = ty * 32 + tx; i < 2304; i += 256)
            bcat[i] = i < 768 ? bq[i] : (i < 1536 ? bk[i - 768] : bv[i - 1536]);
        return;
    }
    const float* W; unsigned short* Wt; int K, N, rel, nx;
    if (blk < 2304) {
        int m = blk / 576; rel = blk - m * 576; K = 768; N = 768; nx = 24;
        W  = m == 0 ? Wq : m == 1 ? Wk : m == 2 ? Wv : Wo;
        Wt = m < 3 ? wqkvT + (size_t)m * 768 * 768 : woT;
    } else if (blk < 4608) {
        rel = blk - 2304; K = 768; N = 3072; nx = 96; W = W1; Wt = w1T;
    } else {
        rel = blk - 4608; K = 3072; N = 768; nx = 24; W = W2; Wt = w2T;
    }
    int n0 = (rel % nx) * 32, k0 = (rel / nx) * 32;
    __shared__ float t[32][33];
#pragma unroll
    for (int i = ty; i < 32; i += 8) t[i][tx] = W[(size_t)(k0 + i) * N + n0 + tx];
    __syncthreads();
#pragma unroll
    for (int i = ty; i < 32; i += 8) Wt[(size_t)(n0 + i) * K + k0 + tx] = f2bf(t[tx][i]);
}

// ---------------- LayerNorm: f32 in -> bf16 out ----------------
__global__ __launch_bounds__(256)
void ln_kernel(const float* __restrict__ x, const float* __restrict__ w,
               const float* __restrict__ b, unsigned short* __restrict__ out) {
    int row = blockIdx.x; size_t base = (size_t)row * 768;
    int tid = threadIdx.x;
    float v0 = x[base + tid], v1 = x[base + tid + 256], v2 = x[base + tid + 512];
    float s1 = v0 + v1 + v2;
    float s2 = v0 * v0 + v1 * v1 + v2 * v2;
#pragma unroll
    for (int off = 32; off > 0; off >>= 1) { s1 += __shfl_xor(s1, off); s2 += __shfl_xor(s2, off); }
    __shared__ float sa[4], sb[4];
    int w4 = tid >> 6;
    if ((tid & 63) == 0) { sa[w4] = s1; sb[w4] = s2; }
    __syncthreads();
    s1 = sa[0] + sa[1] + sa[2] + sa[3];
    s2 = sb[0] + sb[1] + sb[2] + sb[3];
    float mean = s1 * (1.f / 768.f);
    float var  = s2 * (1.f / 768.f) - mean * mean;
    float rstd = rsqrtf(var + 1e-6f);
    out[base + tid]       = f2bf((v0 - mean) * rstd * w[tid]       + b[tid]);
    out[base + tid + 256] = f2bf((v1 - mean) * rstd * w[tid + 256] + b[tid + 256]);
    out[base + tid + 512] = f2bf((v2 - mean) * rstd * w[tid + 512] + b[tid + 512]);
}

// ---------------- GEMM v5: plain T3-minimum 2-phase recipe at reference geometry ----------
// C[M][N] = A[M][K](bf16) * Bt[N][K](bf16)^T + epilogue.
// BM=256, BK=64, 8 waves (512 thr). BN_=256: wave grid 2Mx4N (tile 128x64, 64 MFMA/K-tile);
// BN_=128: wave grid 4Mx2N (tile 64x64, 32 MFMA/K-tile). Double-buffered LDS
// (As 64KB + Bs 64/32KB). Per K-tile: {stage ALL next-tile g2l16 FIRST -> compiler-
// scheduled ds_reads + MFMA cluster -> ONE __syncthreads (drains vmcnt, syncs)}.
// NO inline waitcnt / sched_barrier / setprio (m230/m248-measured recipe: 655-682 TF @K=1024).
// Swizzle: 16B-block phys = log ^ (row&7); write-side via pre-swizzled global source
// (linear LDS dest, rule 21), read-side same XOR (verified conflict-free R5/R7).
// MODE 0: bf16 = acc+bias (cols<768 pre-scaled 0.125); MODE 1: f32 = acc+bias+resid;
// MODE 2: bf16 = gelu(acc+bias).
template<int MODE, int BN_>
__global__ __launch_bounds__(512)
void gemm2ph(const unsigned short* __restrict__ A, const unsigned short* __restrict__ Bt,
             const float* __restrict__ bias, const float* __restrict__ resid,
             void* __restrict__ out, int M, int N, int K) {
    constexpr int BM = 256, BK = 64;
    constexpr int WGN = (BN_ == 256) ? 4 : 2;      // waves along N
    constexpr int WM  = (BN_ == 256) ? 128 : 64;   // wave tile M
    constexpr int WN  = 64;                        // wave tile N
    constexpr int MT  = WM / 16, NT = WN / 16;
    __shared__ unsigned short As[2][BM * BK];
    __shared__ unsigned short Bs[2][BN_ * BK];
    const int tid = threadIdx.x;
    const int l = tid & 63, wid = tid >> 6;
    const int lr = l & 15, lg = l >> 4;
    const int wr = wid / WGN, wc = wid % WGN;
    const int bm0 = blockIdx.y * BM, bn0 = blockIdx.x * BN_;

    const int srow = wid * 8 + (l >> 3);           // row within a 64-row staging call
    const int slb  = (l & 7) ^ (l >> 3);           // pre-swizzled source 16B block

    auto stage = [&](int buf, int kt) {
        const int k0 = kt * BK;
#pragma unroll
        for (int a = 0; a < 4; ++a) {              // A: 4 calls x 64 rows
            int gr = bm0 + a * 64 + srow; gr = gr < M ? gr : M - 1;
            g2l16(A + (size_t)gr * K + k0 + slb * 8, &As[buf][(a * 64 + wid * 8) * BK]);
        }
#pragma unroll
        for (int b = 0; b < BN_ / 64; ++b) {       // B: 4 (or 2) calls x 64 rows
            int gr = bn0 + b * 64 + srow;
            g2l16(Bt + (size_t)gr * K + k0 + slb * 8, &Bs[buf][(b * 64 + wid * 8) * BK]);
        }
    };

    f32x4 acc[MT][NT];
#pragma unroll
    for (int i = 0; i < MT; ++i)
#pragma unroll
        for (int j = 0; j < NT; ++j) acc[i][j] = (f32x4){0.f, 0.f, 0.f, 0.f};

    const int NK = K / BK;
    stage(0, 0);
    __syncthreads();

    const int rsw = lr & 7;                        // read-side row XOR
    for (int kt = 0; kt < NK; ++kt) {
        const int buf = kt & 1;
        if (kt + 1 < NK) stage(buf ^ 1, kt + 1);   // all next-tile stages issued FIRST
        short8 bfr[NT][2];
#pragma unroll
        for (int nt = 0; nt < NT; ++nt)
#pragma unroll
            for (int kk = 0; kk < 2; ++kk)
                bfr[nt][kk] = *(const short8*)&Bs[buf][(wc * WN + nt * 16 + lr) * BK +
                                                       (((kk * 4 + lg) ^ rsw) * 8)];
#pragma unroll
        for (int mt = 0; mt < MT; ++mt) {
            short8 af[2];
#pragma unroll
            for (int kk = 0; kk < 2; ++kk)
                af[kk] = *(const short8*)&As[buf][(wr * WM + mt * 16 + lr) * BK +
                                                  (((kk * 4 + lg) ^ rsw) * 8)];
#pragma unroll
            for (int nt = 0; nt < NT; ++nt)
#pragma unroll
                for (int kk = 0; kk < 2; ++kk)
                    acc[mt][nt] = __builtin_amdgcn_mfma_f32_16x16x32_bf16(
                        af[kk], bfr[nt][kk], acc[mt][nt], 0, 0, 0);
        }
        __syncthreads();                           // one barrier per K-tile (drains vmcnt)
    }

#pragma unroll
    for (int mt = 0; mt < MT; ++mt)
#pragma unroll
        for (int nt = 0; nt < NT; ++nt)
#pragma unroll
            for (int r = 0; r < 4; ++r) {
                int gm = bm0 + wr * WM + mt * 16 + lg * 4 + r;
                int gn = bn0 + wc * WN + nt * 16 + lr;
                if (gm < M) {
                    float c = acc[mt][nt][r] + bias[gn];
                    if (MODE == 0) {
                        if (gn < 768) c *= 0.125f;   // fold 1/sqrt(Dh) into Q
                        ((unsigned short*)out)[(size_t)gm * N + gn] = f2bf(c);
                    } else if (MODE == 1) {
                        ((float*)out)[(size_t)gm * N + gn] = c + resid[(size_t)gm * N + gn];
                    } else {
                        ((unsigned short*)out)[(size_t)gm * N + gn] = f2bf(gelu_f(c));
                    }
                }
            }
}

// ---------------- MFMA attention: one block per (b,h), 4 waves ----------------
__global__ __launch_bounds__(256)
void attn_mfma(const unsigned short* __restrict__ qkv, const int* __restrict__ mask,
               unsigned short* __restrict__ ctx) {
    __shared__ unsigned short Ks[208 * 64];
    __shared__ unsigned short Vt[64 * 256];
    __shared__ unsigned short Psl[4][16 * 40];
    __shared__ float maskadj[224];
    const int bh = blockIdx.x, b = bh / 12, h = bh - b * 12;
    const int tid = threadIdx.x, l = tid & 63, w = tid >> 6;
    const int lr = l & 15, lg = l >> 4;
    const unsigned short* Qg = qkv + (size_t)b * 197 * 2304 + h * 64;
    const unsigned short* Kg = Qg + 768;
    const unsigned short* Vg = Qg + 1536;

    if (tid < 224)
        maskadj[tid] = tid < 197 ? -10000.f * (1.f - (float)mask[b * 197 + tid]) : -1e30f;

    for (int c = w; c < 26; c += 4) {
        int row = c * 8 + (l >> 3);
        int rc = row < 197 ? row : 196;
        int blk = (l & 7) ^ (row & 7);
        g2l16(Kg + (size_t)rc * 2304 + blk * 8, &Ks[c * 8 * 64]);
    }
    {
        int jj = tid >> 3, db = tid & 7;
#pragma unroll
        for (int it = 0; it < 7; ++it) {
            int j = it * 32 + jj;
            short8 v = (short8){0, 0, 0, 0, 0, 0, 0, 0};
            if (j < 197) v = *(const short8*)(Vg + (size_t)j * 2304 + db * 8);
#pragma unroll
            for (int e = 0; e < 8; ++e) {
                int d = db * 8 + e;
                Vt[d * 256 + (((j >> 3) ^ (d & 7)) * 8) + (j & 7)] = (unsigned short)v[e];
            }
        }
    }
    __syncthreads();

    for (int t = w; t < 13; t += 4) {
        const int q0 = t * 16;
        int qr = q0 + lr; qr = qr < 197 ? qr : 196;
        const short8 qf0 = *(const short8*)(Qg + (size_t)qr * 2304 + lg * 8);
        const short8 qf1 = *(const short8*)(Qg + (size_t)qr * 2304 + 32 + lg * 8);

        f32x4 sc[13];
#pragma unroll
        for (int kt = 0; kt < 13; ++kt) {
            const int krow = kt * 16 + lr;
            const short8 kf0 = *(const short8*)&Ks[krow * 64 + ((lg ^ (lr & 7)) * 8)];
            const short8 kf1 = *(const short8*)&Ks[krow * 64 + (((4 + lg) ^ (lr & 7)) * 8)];
            f32x4 a = (f32x4){0.f, 0.f, 0.f, 0.f};
            a = __builtin_amdgcn_mfma_f32_16x16x32_bf16(qf0, kf0, a, 0, 0, 0);
            a = __builtin_amdgcn_mfma_f32_16x16x32_bf16(qf1, kf1, a, 0, 0, 0);
            sc[kt] = a;
        }
        float mx[4] = {-1e30f, -1e30f, -1e30f, -1e30f};
#pragma unroll
        for (int kt = 0; kt < 13; ++kt) {
            float ma = maskadj[kt * 16 + lr];
#pragma unroll
            for (int r = 0; r < 4; ++r) {
                sc[kt][r] += ma;
                mx[r] = fmaxf(mx[r], sc[kt][r]);
            }
        }
#pragma unroll
        for (int r = 0; r < 4; ++r) {
            mx[r] = fmaxf(mx[r], __shfl_xor(mx[r], 1));
            mx[r] = fmaxf(mx[r], __shfl_xor(mx[r], 2));
            mx[r] = fmaxf(mx[r], __shfl_xor(mx[r], 4));
            mx[r] = fmaxf(mx[r], __shfl_xor(mx[r], 8));
        }
        float sm[4] = {0.f, 0.f, 0.f, 0.f};
#pragma unroll
        for (int kt = 0; kt < 13; ++kt)
#pragma unroll
            for (int r = 0; r < 4; ++r) {
                float p = __expf(sc[kt][r] - mx[r]);
                sc[kt][r] = p;
                sm[r] += p;
            }
#pragma unroll
        for (int r = 0; r < 4; ++r) {
            sm[r] += __shfl_xor(sm[r], 1);
            sm[r] += __shfl_xor(sm[r], 2);
            sm[r] += __shfl_xor(sm[r], 4);
            sm[r] += __shfl_xor(sm[r], 8);
            sm[r] = 1.f / sm[r];
        }
        f32x4 ao[4];
#pragma unroll
        for (int dt = 0; dt < 4; ++dt) ao[dt] = (f32x4){0.f, 0.f, 0.f, 0.f};
        unsigned short* Pw = &Psl[w][0];
#pragma unroll
        for (int ks = 0; ks < 7; ++ks) {
#pragma unroll
            for (int tl = 0; tl < 2; ++tl) {
                const int kt = ks * 2 + tl;
#pragma unroll
                for (int r = 0; r < 4; ++r) {
                    unsigned short pv = 0;
                    if (kt < 13) pv = f2bf(sc[kt][r] * sm[r]);
                    Pw[(lg * 4 + r) * 40 + tl * 16 + lr] = pv;
                }
            }
            const short8 pf = *(const short8*)&Pw[lr * 40 + lg * 8];
#pragma unroll
            for (int dt = 0; dt < 4; ++dt) {
                const int drow = dt * 16 + lr;
                const short8 vf = *(const short8*)&Vt[drow * 256 + (((4 * ks + lg) ^ (lr & 7)) * 8)];
                ao[dt] = __builtin_amdgcn_mfma_f32_16x16x32_bf16(vf, pf, ao[dt], 0, 0, 0);
            }
        }
        const int q = q0 + lr;
        if (q < 197) {
            unsigned short* crow = ctx + ((size_t)b * 197 + q) * 768 + h * 64;
#pragma unroll
            for (int dt = 0; dt < 4; ++dt) {
                union { unsigned short u[4]; uint2 v; } pk;
#pragma unroll
                for (int r = 0; r < 4; ++r) pk.u[r] = f2bf(ao[dt][r]);
                *(uint2*)(crow + dt * 16 + lg * 4) = pk.v;
            }
        }
    }
}

extern "C" void kernel_launch(void* const* d_in, const int* in_sizes, int n_in,
                              void* d_out, int out_size, void* d_ws, size_t ws_size,
                              hipStream_t stream) {
    const float* x    = (const float*)d_in[0];
    const float* Wq   = (const float*)d_in[1];
    const float* bq   = (const float*)d_in[2];
    const float* Wk   = (const float*)d_in[3];
    const float* bk   = (const float*)d_in[4];
    const float* Wv   = (const float*)d_in[5];
    const float* bv   = (const float*)d_in[6];
    const float* Wo   = (const float*)d_in[7];
    const float* bo   = (const float*)d_in[8];
    const float* ln1w = (const float*)d_in[9];
    const float* ln1b = (const float*)d_in[10];
    const float* W1   = (const float*)d_in[11];
    const float* b1   = (const float*)d_in[12];
    const float* W2   = (const float*)d_in[13];
    const float* b2   = (const float*)d_in[14];
    const float* ln2w = (const float*)d_in[15];
    const float* ln2b = (const float*)d_in[16];
    const int*   mask = (const int*)d_in[17];

    size_t off = 0;
    auto nxt = [&](size_t bytes) -> void* {
        void* r = (char*)d_ws + off; off += (bytes + 255) & ~(size_t)255; return r;
    };
    unsigned short* hbuf  = (unsigned short*)nxt((size_t)BS_ * 768 * 2);
    unsigned short* qkvg  = (unsigned short*)nxt((size_t)BS_ * 3072 * 2);  // QKV (2304), reused for FFN1 out (3072)
    unsigned short* wqkvT = (unsigned short*)nxt((size_t)2304 * 768 * 2);
    unsigned short* woT   = (unsigned short*)nxt((size_t)768 * 768 * 2);
    unsigned short* w1T   = (unsigned short*)nxt((size_t)3072 * 768 * 2);
    unsigned short* w2T   = (unsigned short*)nxt((size_t)768 * 3072 * 2);
    float*          bcat  = (float*)nxt(2304 * 4);
    unsigned short* ctx   = (unsigned short*)nxt((size_t)BS_ * 768 * 2);
    (void)ws_size; (void)in_sizes; (void)n_in; (void)out_size;

    transpose_all<<<6913, dim3(32, 8), 0, stream>>>(Wq, Wk, Wv, Wo, W1, W2, bq, bk, bv,
                                                    wqkvT, woT, w1T, w2T, bcat);
    ln_kernel<<<BS_, 256, 0, stream>>>(x, ln1w, ln1b, hbuf);
    gemm2ph<0, 256><<<dim3(9, 50), 512, 0, stream>>>(hbuf, wqkvT, bcat, nullptr, qkvg, BS_, 2304, 768);
    attn_mfma<<<768, 256, 0, stream>>>(qkvg, mask, ctx);
    gemm2ph<1, 128><<<dim3(6, 50), 512, 0, stream>>>(ctx, woT, bo, x, d_out, BS_, 768, 768);
    ln_kernel<<<BS_, 256, 0, stream>>>((const float*)d_out, ln2w, ln2b, hbuf);
    gemm2ph<2, 256><<<dim3(12, 50), 512, 0, stream>>>(hbuf, w1T, b1, nullptr, qkvg, BS_, 3072, 768);
    gemm2ph<1, 128><<<dim3(6, 50), 512, 0, stream>>>(qkvg, w2T, b2, (const float*)d_out, d_out, BS_, 768, 3072);
}

// Round 9
// 475.139 us; speedup vs baseline: 1.2133x; 1.1095x over previous
//
#include <hip/hip_runtime.h>
#include <stdint.h>

#define B_   64
#define S_   197
#define D_   768
#define H_   12
#define F_   3072
#define BS_  (B_ * S_)   // 12608

typedef __attribute__((ext_vector_type(8))) short short8;
typedef __attribute__((ext_vector_type(4))) float f32x4;

__device__ __forceinline__ float bf2f(unsigned short h) {
    union { unsigned int u; float f; } v; v.u = ((unsigned int)h) << 16; return v.f;
}
__device__ __forceinline__ unsigned short f2bf(float f) {
    union { float f; unsigned int u; } v; v.f = f;
    unsigned int r = v.u + 0x7FFFu + ((v.u >> 16) & 1u);
    return (unsigned short)(r >> 16);
}

__device__ __forceinline__ void g2l16(const void* g, void* l) {
    __builtin_amdgcn_global_load_lds(
        (const __attribute__((address_space(1))) unsigned int*)g,
        (__attribute__((address_space(3))) unsigned int*)l, 16, 0, 0);
}

// exact-enough GELU: A&S 7.1.26 erf (max abs err 1.5e-7)
__device__ __forceinline__ float gelu_f(float c) {
    float z = fabsf(c) * 0.70710678118f;
    float t = __builtin_amdgcn_rcpf(1.f + 0.3275911f * z);
    float p = ((((1.061405429f * t - 1.453152027f) * t + 1.421413741f) * t
               - 0.284496736f) * t + 0.254829592f) * t;
    float erfv = 1.f - p * __expf(-z * z);
    erfv = c < 0.f ? -erfv : erfv;
    return 0.5f * c * (1.f + erfv);
}

// ---------------- fused weight transpose + bf16 cast + bias concat ----------------
__global__ __launch_bounds__(256)
void transpose_all(const float* __restrict__ Wq, const float* __restrict__ Wk,
                   const float* __restrict__ Wv, const float* __restrict__ Wo,
                   const float* __restrict__ W1, const float* __restrict__ W2,
                   const float* __restrict__ bq, const float* __restrict__ bk,
                   const float* __restrict__ bv,
                   unsigned short* __restrict__ wqkvT, unsigned short* __restrict__ woT,
                   unsigned short* __restrict__ w1T, unsigned short* __restrict__ w2T,
                   float* __restrict__ bcat) {
    int blk = blockIdx.x;
    int tx = threadIdx.x, ty = threadIdx.y;
    if (blk == 6912) {
        for (int i = ty * 32 + tx; i < 2304; i += 256)
            bcat[i] = i < 768 ? bq[i] : (i < 1536 ? bk[i - 768] : bv[i - 1536]);
        return;
    }
    const float* W; unsigned short* Wt; int K, N, rel, nx;
    if (blk < 2304) {
        int m = blk / 576; rel = blk - m * 576; K = 768; N = 768; nx = 24;
        W  = m == 0 ? Wq : m == 1 ? Wk : m == 2 ? Wv : Wo;
        Wt = m < 3 ? wqkvT + (size_t)m * 768 * 768 : woT;
    } else if (blk < 4608) {
        rel = blk - 2304; K = 768; N = 3072; nx = 96; W = W1; Wt = w1T;
    } else {
        rel = blk - 4608; K = 3072; N = 768; nx = 24; W = W2; Wt = w2T;
    }
    int n0 = (rel % nx) * 32, k0 = (rel / nx) * 32;
    __shared__ float t[32][33];
#pragma unroll
    for (int i = ty; i < 32; i += 8) t[i][tx] = W[(size_t)(k0 + i) * N + n0 + tx];
    __syncthreads();
#pragma unroll
    for (int i = ty; i < 32; i += 8) Wt[(size_t)(n0 + i) * K + k0 + tx] = f2bf(t[tx][i]);
}

// ---------------- LayerNorm: f32 in -> bf16 out ----------------
__global__ __launch_bounds__(256)
void ln_kernel(const float* __restrict__ x, const float* __restrict__ w,
               const float* __restrict__ b, unsigned short* __restrict__ out) {
    int row = blockIdx.x; size_t base = (size_t)row * 768;
    int tid = threadIdx.x;
    float v0 = x[base + tid], v1 = x[base + tid + 256], v2 = x[base + tid + 512];
    float s1 = v0 + v1 + v2;
    float s2 = v0 * v0 + v1 * v1 + v2 * v2;
#pragma unroll
    for (int off = 32; off > 0; off >>= 1) { s1 += __shfl_xor(s1, off); s2 += __shfl_xor(s2, off); }
    __shared__ float sa[4], sb[4];
    int w4 = tid >> 6;
    if ((tid & 63) == 0) { sa[w4] = s1; sb[w4] = s2; }
    __syncthreads();
    s1 = sa[0] + sa[1] + sa[2] + sa[3];
    s2 = sb[0] + sb[1] + sb[2] + sb[3];
    float mean = s1 * (1.f / 768.f);
    float var  = s2 * (1.f / 768.f) - mean * mean;
    float rstd = rsqrtf(var + 1e-6f);
    out[base + tid]       = f2bf((v0 - mean) * rstd * w[tid]       + b[tid]);
    out[base + tid + 256] = f2bf((v1 - mean) * rstd * w[tid + 256] + b[tid + 256]);
    out[base + tid + 512] = f2bf((v2 - mean) * rstd * w[tid + 512] + b[tid + 512]);
}

// ---------------- GEMM v6: L2-serpentine block order, BK=32, multi-block/CU -------------
// C[M][N] = A[M][K](bf16) * Bt[N][K](bf16)^T + epilogue. 8 waves (512 thr).
// Block order (the round's ONE lever): ranks = {for each N-super of NSUP col-tiles:
// all M-tiles ascending, N minor} then m204 XCD-chunked -> each XCD sweeps a long
// M-slab against an L2-resident B-super (<=2.4MB). Cuts A re-fetch from ~nN x to
// ~supers x and keeps staged traffic in L2 (cures the measured 10-12 B/cyc/CU =
// HBM-rate staging invariant of R3-R8).
// BK=32 (R4-proven conflict-free swizzle: phys 16B-blk = log ^ ((row>>1)&3), both-sides),
// LDS 64/48/32 KB -> 2-5 blocks/CU. Plain 2-phase K-loop (stage-first, one barrier).
// MODE 0: bf16 = acc+bias (cols<768 pre-scaled 0.125); MODE 1: f32 = acc+bias+resid;
// MODE 2: bf16 = gelu(acc+bias).
template<int MODE, int BM_, int BN_>
__global__ __launch_bounds__(512)
void gemmL2(const unsigned short* __restrict__ A, const unsigned short* __restrict__ Bt,
            const float* __restrict__ bias, const float* __restrict__ resid,
            void* __restrict__ out, int M, int N, int K, int NSUP) {
    constexpr int BK = 32;
    constexpr int WGN = (BN_ == 256) ? 4 : 2;
    constexpr int WGM = 8 / WGN;
    constexpr int WM = BM_ / WGM, WN = BN_ / WGN;
    constexpr int MT = WM / 16, NT = WN / 16;
    __shared__ unsigned short As[2][BM_ * BK];
    __shared__ unsigned short Bs[2][BN_ * BK];
    const int tid = threadIdx.x;
    const int l = tid & 63, wid = tid >> 6;
    const int lr = l & 15, lg = l >> 4;
    const int wr = wid / WGN, wc = wid % WGN;

    // ---- rank = m204 XCD-chunk of linear id; decode rank via N-super serpentine ----
    const int nN = gridDim.x, nM = gridDim.y;
    const int nTot = nN * nM;
    const int orig = blockIdx.x + nN * blockIdx.y;
    const int q8 = nTot >> 3, r8 = nTot & 7;
    const int xcd = orig & 7, idx = orig >> 3;
    const int rank = (xcd < r8 ? xcd * (q8 + 1) : r8 * (q8 + 1) + (xcd - r8) * q8) + idx;
    const int fullg = nM * NSUP;
    const int sup = rank / fullg;
    const int rem = rank - sup * fullg;
    const int n0s = sup * NSUP;
    int wsup = nN - n0s; if (wsup > NSUP) wsup = NSUP;
    const int mloc = rem / wsup;
    const int nloc = rem - mloc * wsup;
    const int bm0 = mloc * BM_;
    const int bn0 = (n0s + nloc) * BN_;

    // ---- staging: each call covers 128 rows x 32 cols (512 thr x 16B) ----
    const int srow = tid >> 2;                       // 0..127
    const int slb  = (tid & 3) ^ ((tid >> 3) & 3);   // pre-swizzled logical 16B block
    auto stage = [&](int buf, int kt) {
        const int k0 = kt * BK;
#pragma unroll
        for (int c = 0; c < BM_ / 128; ++c) {
            int gr = bm0 + c * 128 + srow; gr = gr < M ? gr : M - 1;
            g2l16(A + (size_t)gr * K + k0 + slb * 8, &As[buf][(c * 128 + srow) * BK]);
        }
#pragma unroll
        for (int c = 0; c < BN_ / 128; ++c) {
            int gr = bn0 + c * 128 + srow;
            g2l16(Bt + (size_t)gr * K + k0 + slb * 8, &Bs[buf][(c * 128 + srow) * BK]);
        }
    };

    f32x4 acc[MT][NT];
#pragma unroll
    for (int i = 0; i < MT; ++i)
#pragma unroll
        for (int j = 0; j < NT; ++j) acc[i][j] = (f32x4){0.f, 0.f, 0.f, 0.f};

    const int NK = K / BK;
    stage(0, 0);
    __syncthreads();

    const int rsw = (lr >> 1) & 3;                   // read-side block XOR
    for (int kt = 0; kt < NK; ++kt) {
        const int buf = kt & 1;
        if (kt + 1 < NK) stage(buf ^ 1, kt + 1);     // next-tile stages issued FIRST
        short8 bfr[NT];
#pragma unroll
        for (int nt = 0; nt < NT; ++nt)
            bfr[nt] = *(const short8*)&Bs[buf][(wc * WN + nt * 16 + lr) * BK + ((lg ^ rsw) * 8)];
#pragma unroll
        for (int mt = 0; mt < MT; ++mt) {
            const short8 af = *(const short8*)&As[buf][(wr * WM + mt * 16 + lr) * BK + ((lg ^ rsw) * 8)];
#pragma unroll
            for (int nt = 0; nt < NT; ++nt)
                acc[mt][nt] = __builtin_amdgcn_mfma_f32_16x16x32_bf16(af, bfr[nt], acc[mt][nt], 0, 0, 0);
        }
        __syncthreads();                             // one barrier per K-tile
    }

#pragma unroll
    for (int mt = 0; mt < MT; ++mt)
#pragma unroll
        for (int nt = 0; nt < NT; ++nt)
#pragma unroll
            for (int r = 0; r < 4; ++r) {
                int gm = bm0 + wr * WM + mt * 16 + lg * 4 + r;
                int gn = bn0 + wc * WN + nt * 16 + lr;
                if (gm < M) {
                    float c = acc[mt][nt][r] + bias[gn];
                    if (MODE == 0) {
                        if (gn < 768) c *= 0.125f;   // fold 1/sqrt(Dh) into Q
                        ((unsigned short*)out)[(size_t)gm * N + gn] = f2bf(c);
                    } else if (MODE == 1) {
                        ((float*)out)[(size_t)gm * N + gn] = c + resid[(size_t)gm * N + gn];
                    } else {
                        ((unsigned short*)out)[(size_t)gm * N + gn] = f2bf(gelu_f(c));
                    }
                }
            }
}

// ---------------- MFMA attention: one block per (b,h), 4 waves ----------------
__global__ __launch_bounds__(256)
void attn_mfma(const unsigned short* __restrict__ qkv, const int* __restrict__ mask,
               unsigned short* __restrict__ ctx) {
    __shared__ unsigned short Ks[208 * 64];
    __shared__ unsigned short Vt[64 * 256];
    __shared__ unsigned short Psl[4][16 * 40];
    __shared__ float maskadj[224];
    const int bh = blockIdx.x, b = bh / 12, h = bh - b * 12;
    const int tid = threadIdx.x, l = tid & 63, w = tid >> 6;
    const int lr = l & 15, lg = l >> 4;
    const unsigned short* Qg = qkv + (size_t)b * 197 * 2304 + h * 64;
    const unsigned short* Kg = Qg + 768;
    const unsigned short* Vg = Qg + 1536;

    if (tid < 224)
        maskadj[tid] = tid < 197 ? -10000.f * (1.f - (float)mask[b * 197 + tid]) : -1e30f;

    for (int c = w; c < 26; c += 4) {
        int row = c * 8 + (l >> 3);
        int rc = row < 197 ? row : 196;
        int blk = (l & 7) ^ (row & 7);
        g2l16(Kg + (size_t)rc * 2304 + blk * 8, &Ks[c * 8 * 64]);
    }
    {
        int jj = tid >> 3, db = tid & 7;
#pragma unroll
        for (int it = 0; it < 7; ++it) {
            int j = it * 32 + jj;
            short8 v = (short8){0, 0, 0, 0, 0, 0, 0, 0};
            if (j < 197) v = *(const short8*)(Vg + (size_t)j * 2304 + db * 8);
#pragma unroll
            for (int e = 0; e < 8; ++e) {
                int d = db * 8 + e;
                Vt[d * 256 + (((j >> 3) ^ (d & 7)) * 8) + (j & 7)] = (unsigned short)v[e];
            }
        }
    }
    __syncthreads();

    for (int t = w; t < 13; t += 4) {
        const int q0 = t * 16;
        int qr = q0 + lr; qr = qr < 197 ? qr : 196;
        const short8 qf0 = *(const short8*)(Qg + (size_t)qr * 2304 + lg * 8);
        const short8 qf1 = *(const short8*)(Qg + (size_t)qr * 2304 + 32 + lg * 8);

        f32x4 sc[13];
#pragma unroll
        for (int kt = 0; kt < 13; ++kt) {
            const int krow = kt * 16 + lr;
            const short8 kf0 = *(const short8*)&Ks[krow * 64 + ((lg ^ (lr & 7)) * 8)];
            const short8 kf1 = *(const short8*)&Ks[krow * 64 + (((4 + lg) ^ (lr & 7)) * 8)];
            f32x4 a = (f32x4){0.f, 0.f, 0.f, 0.f};
            a = __builtin_amdgcn_mfma_f32_16x16x32_bf16(qf0, kf0, a, 0, 0, 0);
            a = __builtin_amdgcn_mfma_f32_16x16x32_bf16(qf1, kf1, a, 0, 0, 0);
            sc[kt] = a;
        }
        float mx[4] = {-1e30f, -1e30f, -1e30f, -1e30f};
#pragma unroll
        for (int kt = 0; kt < 13; ++kt) {
            float ma = maskadj[kt * 16 + lr];
#pragma unroll
            for (int r = 0; r < 4; ++r) {
                sc[kt][r] += ma;
                mx[r] = fmaxf(mx[r], sc[kt][r]);
            }
        }
#pragma unroll
        for (int r = 0; r < 4; ++r) {
            mx[r] = fmaxf(mx[r], __shfl_xor(mx[r], 1));
            mx[r] = fmaxf(mx[r], __shfl_xor(mx[r], 2));
            mx[r] = fmaxf(mx[r], __shfl_xor(mx[r], 4));
            mx[r] = fmaxf(mx[r], __shfl_xor(mx[r], 8));
        }
        float sm[4] = {0.f, 0.f, 0.f, 0.f};
#pragma unroll
        for (int kt = 0; kt < 13; ++kt)
#pragma unroll
            for (int r = 0; r < 4; ++r) {
                float p = __expf(sc[kt][r] - mx[r]);
                sc[kt][r] = p;
                sm[r] += p;
            }
#pragma unroll
        for (int r = 0; r < 4; ++r) {
            sm[r] += __shfl_xor(sm[r], 1);
            sm[r] += __shfl_xor(sm[r], 2);
            sm[r] += __shfl_xor(sm[r], 4);
            sm[r] += __shfl_xor(sm[r], 8);
            sm[r] = 1.f / sm[r];
        }
        f32x4 ao[4];
#pragma unroll
        for (int dt = 0; dt < 4; ++dt) ao[dt] = (f32x4){0.f, 0.f, 0.f, 0.f};
        unsigned short* Pw = &Psl[w][0];
#pragma unroll
        for (int ks = 0; ks < 7; ++ks) {
#pragma unroll
            for (int tl = 0; tl < 2; ++tl) {
                const int kt = ks * 2 + tl;
#pragma unroll
                for (int r = 0; r < 4; ++r) {
                    unsigned short pv = 0;
                    if (kt < 13) pv = f2bf(sc[kt][r] * sm[r]);
                    Pw[(lg * 4 + r) * 40 + tl * 16 + lr] = pv;
                }
            }
            const short8 pf = *(const short8*)&Pw[lr * 40 + lg * 8];
#pragma unroll
            for (int dt = 0; dt < 4; ++dt) {
                const int drow = dt * 16 + lr;
                const short8 vf = *(const short8*)&Vt[drow * 256 + (((4 * ks + lg) ^ (lr & 7)) * 8)];
                ao[dt] = __builtin_amdgcn_mfma_f32_16x16x32_bf16(vf, pf, ao[dt], 0, 0, 0);
            }
        }
        const int q = q0 + lr;
        if (q < 197) {
            unsigned short* crow = ctx + ((size_t)b * 197 + q) * 768 + h * 64;
#pragma unroll
            for (int dt = 0; dt < 4; ++dt) {
                union { unsigned short u[4]; uint2 v; } pk;
#pragma unroll
                for (int r = 0; r < 4; ++r) pk.u[r] = f2bf(ao[dt][r]);
                *(uint2*)(crow + dt * 16 + lg * 4) = pk.v;
            }
        }
    }
}

extern "C" void kernel_launch(void* const* d_in, const int* in_sizes, int n_in,
                              void* d_out, int out_size, void* d_ws, size_t ws_size,
                              hipStream_t stream) {
    const float* x    = (const float*)d_in[0];
    const float* Wq   = (const float*)d_in[1];
    const float* bq   = (const float*)d_in[2];
    const float* Wk   = (const float*)d_in[3];
    const float* bk   = (const float*)d_in[4];
    const float* Wv   = (const float*)d_in[5];
    const float* bv   = (const float*)d_in[6];
    const float* Wo   = (const float*)d_in[7];
    const float* bo   = (const float*)d_in[8];
    const float* ln1w = (const float*)d_in[9];
    const float* ln1b = (const float*)d_in[10];
    const float* W1   = (const float*)d_in[11];
    const float* b1   = (const float*)d_in[12];
    const float* W2   = (const float*)d_in[13];
    const float* b2   = (const float*)d_in[14];
    const float* ln2w = (const float*)d_in[15];
    const float* ln2b = (const float*)d_in[16];
    const int*   mask = (const int*)d_in[17];

    size_t off = 0;
    auto nxt = [&](size_t bytes) -> void* {
        void* r = (char*)d_ws + off; off += (bytes + 255) & ~(size_t)255; return r;
    };
    unsigned short* hbuf  = (unsigned short*)nxt((size_t)BS_ * 768 * 2);
    unsigned short* qkvg  = (unsigned short*)nxt((size_t)BS_ * 3072 * 2);  // QKV (2304), reused for FFN1 out (3072)
    unsigned short* wqkvT = (unsigned short*)nxt((size_t)2304 * 768 * 2);
    unsigned short* woT   = (unsigned short*)nxt((size_t)768 * 768 * 2);
    unsigned short* w1T   = (unsigned short*)nxt((size_t)3072 * 768 * 2);
    unsigned short* w2T   = (unsigned short*)nxt((size_t)768 * 3072 * 2);
    float*          bcat  = (float*)nxt(2304 * 4);
    unsigned short* ctx   = (unsigned short*)nxt((size_t)BS_ * 768 * 2);
    (void)ws_size; (void)in_sizes; (void)n_in; (void)out_size;

    transpose_all<<<6913, dim3(32, 8), 0, stream>>>(Wq, Wk, Wv, Wo, W1, W2, bq, bk, bv,
                                                    wqkvT, woT, w1T, w2T, bcat);
    ln_kernel<<<BS_, 256, 0, stream>>>(x, ln1w, ln1b, hbuf);
    // QKV: N=2304, BN=256 -> nN=9, NSUP=5 (B-super 2.0MB)
    gemmL2<0, 256, 256><<<dim3(9, 50), 512, 0, stream>>>(hbuf, wqkvT, bcat, nullptr, qkvg, BS_, 2304, 768, 5);
    attn_mfma<<<768, 256, 0, stream>>>(qkvg, mask, ctx);
    // O-proj: N=768, BM=128/BN=128 -> (6,99), NSUP=6 (whole B 1.2MB resident)
    gemmL2<1, 128, 128><<<dim3(6, 99), 512, 0, stream>>>(ctx, woT, bo, x, d_out, BS_, 768, 768, 6);
    ln_kernel<<<BS_, 256, 0, stream>>>((const float*)d_out, ln2w, ln2b, hbuf);
    // FFN1: N=3072, BN=256 -> nN=12, NSUP=6 (B-super 2.4MB, 2 supers -> A fetched 2x)
    gemmL2<2, 256, 256><<<dim3(12, 50), 512, 0, stream>>>(hbuf, w1T, b1, nullptr, qkvg, BS_, 3072, 768, 6);
    // FFN2: K=3072, N=768, BN=128 -> nN=6, NSUP=3 (B-super 2.4MB)
    gemmL2<1, 256, 128><<<dim3(6, 50), 512, 0, stream>>>(qkvg, w2T, b2, (const float*)d_out, d_out, BS_, 768, 3072, 3);
}